// Round 1
// baseline (167.079 us; speedup 1.0000x reference)
//
#include <hip/hip_runtime.h>
#include <hip/hip_bf16.h>
#include <math.h>

// Problem constants
#define NB 8
#define NN 225
#define NT 1800          // NB*NN
#define HID 64
#define NE 14400
#define NP 50625         // NN*NN
#define HA 32
#define HC 32
#define BN_EPS 1e-5f

// -------- workspace layout (float offsets) --------
// zeroed region:
#define WS_AGG0   0         // 1800*2   = 3600
#define WS_AGG1   3600      // 1800*64  = 115200
#define WS_SUM0   118800    // 64
#define WS_SQ0    118864    // 64
#define WS_SUM1   118928    // 64
#define WS_SQ1    118992    // 64
#define WS_ZERO_FLOATS 119056
// non-zeroed:
#define WS_PM     119056    // 8*25*2 = 400 (per-chunk max,sum)
#define WS_MS     119456    // 8*2 = 16 (global max, 1/sum)
#define WS_TPRE   119472    // 115200
#define WS_H1     234672    // 115200
#define WS_FEATS  349872    // 115200
#define WS_P1     465072    // 57600
#define WS_P2     522672    // 57600
#define WS_PS     580272    // 256

// ---------------- layer 0 scatter: agg0[dst] += x[src] (2 ch) ----------------
__global__ void k_scatter0(const float* __restrict__ x, const int* __restrict__ ei,
                           float* __restrict__ agg0) {
    int t = blockIdx.x * blockDim.x + threadIdx.x;
    if (t >= NE * 2) return;
    int e = t >> 1, c = t & 1;
    int src = ei[e], dst = ei[NE + e];
    atomicAdd(&agg0[dst * 2 + c], x[src * 2 + c]);
}

// ---------------- layer 0 linear (2->64) + BN stats ----------------
__global__ void k_lin0(const float* __restrict__ x, const float* __restrict__ agg0,
                       const float* __restrict__ w1, const float* __restrict__ b1,
                       float* __restrict__ tpre, float* __restrict__ ssum, float* __restrict__ ssq) {
    __shared__ float red[512];
    int c = threadIdx.x & 63, rg = threadIdx.x >> 6;  // 0..3
    int base = blockIdx.x * 16;
    float w0 = w1[c], w1c = w1[64 + c], bc = b1[c];
    float ls = 0.f, lq = 0.f;
    for (int rr = rg; rr < 16; rr += 4) {
        int r = base + rr;
        if (r < NT) {
            float i0 = x[r * 2] + agg0[r * 2];
            float i1 = x[r * 2 + 1] + agg0[r * 2 + 1];
            float v = bc + i0 * w0 + i1 * w1c;
            tpre[r * 64 + c] = v;
            ls += v; lq += v * v;
        }
    }
    red[threadIdx.x] = ls; red[256 + threadIdx.x] = lq;
    __syncthreads();
    if (threadIdx.x < 64) {
        float s = red[c] + red[64 + c] + red[128 + c] + red[192 + c];
        float q = red[256 + c] + red[320 + c] + red[384 + c] + red[448 + c];
        atomicAdd(&ssum[c], s);
        atomicAdd(&ssq[c], q);
    }
}

// ---------------- layer 0 BN + ReLU + linear (64->64) ----------------
__global__ void k_bnlin0(const float* __restrict__ tpre, const float* __restrict__ ssum,
                         const float* __restrict__ ssq, const float* __restrict__ gamma,
                         const float* __restrict__ beta, const float* __restrict__ w2,
                         const float* __restrict__ b2, float* __restrict__ h1) {
    __shared__ float y[4][64];
    int c = threadIdx.x & 63, rg = threadIdx.x >> 6;
    int r = blockIdx.x * 4 + rg;   // 450*4 = 1800 exact
    float m = ssum[c] * (1.f / NT);
    float v = ssq[c] * (1.f / NT) - m * m;
    float inv = rsqrtf(v + BN_EPS);
    float yv = (tpre[r * 64 + c] - m) * inv * gamma[c] + beta[c];
    y[rg][c] = fmaxf(yv, 0.f);
    __syncthreads();
    float acc = b2[c];
#pragma unroll
    for (int k = 0; k < 64; ++k) acc += y[rg][k] * w2[k * 64 + c];
    h1[r * 64 + c] = acc;
}

// ---------------- layer 1 scatter: agg1[dst] += h1[src] (64 ch, float4) ----------------
__global__ void k_scatter1(const float* __restrict__ h1, const int* __restrict__ ei,
                           float* __restrict__ agg1) {
    int t = blockIdx.x * blockDim.x + threadIdx.x;
    int e = t >> 4, q = t & 15;
    if (e >= NE) return;
    int src = ei[e], dst = ei[NE + e];
    const float4 v = ((const float4*)h1)[src * 16 + q];
    float* a = &agg1[dst * 64 + q * 4];
    atomicAdd(a + 0, v.x); atomicAdd(a + 1, v.y);
    atomicAdd(a + 2, v.z); atomicAdd(a + 3, v.w);
}

// ---------------- layer 1 linear (64->64) + BN stats ----------------
__global__ void k_lin1(const float* __restrict__ h1, const float* __restrict__ agg1,
                       const float* __restrict__ w1, const float* __restrict__ b1,
                       float* __restrict__ tpre, float* __restrict__ ssum, float* __restrict__ ssq) {
    __shared__ float in[16][64];
    __shared__ float red[512];
    int c = threadIdx.x & 63, rg = threadIdx.x >> 6;
    int base = blockIdx.x * 16;
    for (int rr = rg; rr < 16; rr += 4) {
        int r = base + rr;
        in[rr][c] = (r < NT) ? (h1[r * 64 + c] + agg1[r * 64 + c]) : 0.f;
    }
    __syncthreads();
    float ls = 0.f, lq = 0.f;
    for (int rr = rg; rr < 16; rr += 4) {
        int r = base + rr;
        if (r < NT) {
            float acc = b1[c];
#pragma unroll
            for (int k = 0; k < 64; ++k) acc += in[rr][k] * w1[k * 64 + c];
            tpre[r * 64 + c] = acc;
            ls += acc; lq += acc * acc;
        }
    }
    red[threadIdx.x] = ls; red[256 + threadIdx.x] = lq;
    __syncthreads();
    if (threadIdx.x < 64) {
        float s = red[c] + red[64 + c] + red[128 + c] + red[192 + c];
        float q = red[256 + c] + red[320 + c] + red[384 + c] + red[448 + c];
        atomicAdd(&ssum[c], s);
        atomicAdd(&ssq[c], q);
    }
}

// ---------------- layer 1 BN + ReLU + linear (64->64) + actor node projections ----------------
__global__ void k_bnlin1proj(const float* __restrict__ tpre, const float* __restrict__ ssum,
                             const float* __restrict__ ssq, const float* __restrict__ gamma,
                             const float* __restrict__ beta, const float* __restrict__ w2,
                             const float* __restrict__ b2, const float* __restrict__ a_w1,
                             float* __restrict__ feats, float* __restrict__ P1,
                             float* __restrict__ P2) {
    __shared__ float y[4][64];
    __shared__ float f[4][64];
    int c = threadIdx.x & 63, rg = threadIdx.x >> 6;
    int r = blockIdx.x * 4 + rg;   // 450*4 = 1800 exact
    float m = ssum[c] * (1.f / NT);
    float v = ssq[c] * (1.f / NT) - m * m;
    float inv = rsqrtf(v + BN_EPS);
    float yv = (tpre[r * 64 + c] - m) * inv * gamma[c] + beta[c];
    y[rg][c] = fmaxf(yv, 0.f);
    __syncthreads();
    float acc = b2[c];
#pragma unroll
    for (int k = 0; k < 64; ++k) acc += y[rg][k] * w2[k * 64 + c];
    feats[r * 64 + c] = acc;
    f[rg][c] = acc;
    __syncthreads();
    // P1 uses a_w1 rows [64,128) (nodes1 = j = p%225), P2 uses rows [128,192) (nodes2 = i = p/225)
    int j = c & 31;
    const float* wbase = (c < 32) ? (a_w1 + 64 * HA) : (a_w1 + 128 * HA);
    float p = 0.f;
#pragma unroll
    for (int k = 0; k < 64; ++k) p += f[rg][k] * wbase[k * HA + j];
    if (c < 32) P1[r * HA + j] = p;
    else        P2[r * HA + j] = p;
}

// ---------------- graph pooling + critic head + actor state projection ----------------
__global__ void k_heads(const float* __restrict__ feats, const float* __restrict__ a_w1,
                        const float* __restrict__ a_b1, const float* __restrict__ c_w1,
                        const float* __restrict__ c_b1, const float* __restrict__ c_w2,
                        const float* __restrict__ c_b2, float* __restrict__ Ps,
                        float* __restrict__ value_out) {
    __shared__ float emb[NB][64];
    __shared__ float hv[NB][HC];
    int t = threadIdx.x;
    int b = t >> 6, c = t & 63;
    float s = 0.f;
    const float* fp = feats + (b * NN) * 64 + c;
    for (int n = 0; n < NN; ++n) s += fp[n * 64];
    emb[b][c] = s * (1.f / NN);
    __syncthreads();
    if (t < 256) {
        int bb = t >> 5, j = t & 31;
        float acc = a_b1[j];
#pragma unroll
        for (int k = 0; k < 64; ++k) acc += emb[bb][k] * a_w1[k * HA + j];
        Ps[bb * HA + j] = acc;   // includes actor bias
    } else {
        int t2 = t - 256;
        int bb = t2 >> 5, j = t2 & 31;
        float acc = c_b1[j];
#pragma unroll
        for (int k = 0; k < 64; ++k) acc += emb[bb][k] * c_w1[k * HC + j];
        hv[bb][j] = fmaxf(acc, 0.f);
    }
    __syncthreads();
    if (t < NB) {
        float acc = c_b2[0];
#pragma unroll
        for (int j = 0; j < HC; ++j) acc += hv[t][j] * c_w2[j];
        value_out[t] = acc;
    }
}

// ---------------- pairwise actor logits + per-chunk online softmax stats ----------------
// 25 blocks per batch; each block handles 9 consecutive i-rows (9*225 = 2025 pairs)
__global__ void k_pairs(const float* __restrict__ P1, const float* __restrict__ P2,
                        const float* __restrict__ Ps, const float* __restrict__ a_w2,
                        const float* __restrict__ a_b2, float* __restrict__ logits_out,
                        float* __restrict__ pm) {
    __shared__ float P1s[NN * 33];   // padded stride 33: bank = (j+k)%32, conflict-free
    __shared__ float P2s[9 * 32];
    __shared__ float Psl[32], w2l[32];
    __shared__ float red[256];
    int b = blockIdx.x / 25, chunk = blockIdx.x % 25;
    int t = threadIdx.x;
    for (int idx = t; idx < NN * 32; idx += 256) {
        int j = idx >> 5, k = idx & 31;
        P1s[j * 33 + k] = P1[(b * NN + j) * 32 + k];
    }
    for (int idx = t; idx < 9 * 32; idx += 256)
        P2s[idx] = P2[(b * NN + chunk * 9) * 32 + idx];
    if (t < 32) { Psl[t] = Ps[b * 32 + t]; w2l[t] = a_w2[t]; }
    __syncthreads();
    float bias2 = a_b2[0];
    float* lg = logits_out + b * NP + chunk * 2025;
    float lvals[8];
    float lmax = -1e30f;
    for (int p = t, it = 0; p < 2025; p += 256, ++it) {
        int i = p / 225, j = p % 225;
        float acc = bias2;
#pragma unroll
        for (int k = 0; k < 32; ++k) {
            float h = Psl[k] + P1s[j * 33 + k] + P2s[i * 32 + k];
            acc += fmaxf(h, 0.f) * w2l[k];
        }
        lg[p] = acc;
        lvals[it] = acc;
        lmax = fmaxf(lmax, acc);
    }
    red[t] = lmax; __syncthreads();
    for (int s = 128; s > 0; s >>= 1) {
        if (t < s) red[t] = fmaxf(red[t], red[t + s]);
        __syncthreads();
    }
    float M = red[0];
    __syncthreads();
    float ls = 0.f;
    for (int p = t, it = 0; p < 2025; p += 256, ++it)
        ls += expf(lvals[it] - M);
    red[t] = ls; __syncthreads();
    for (int s = 128; s > 0; s >>= 1) {
        if (t < s) red[t] += red[t + s];
        __syncthreads();
    }
    if (t == 0) {
        pm[(b * 25 + chunk) * 2] = M;
        pm[(b * 25 + chunk) * 2 + 1] = red[0];
    }
}

// ---------------- combine per-chunk (m,s) -> global (M, 1/S) per batch ----------------
__global__ void k_combine(const float* __restrict__ pm, float* __restrict__ MS) {
    int t = threadIdx.x;
    if (t < NB) {
        float M = -1e30f;
        for (int c = 0; c < 25; ++c) M = fmaxf(M, pm[(t * 25 + c) * 2]);
        float S = 0.f;
        for (int c = 0; c < 25; ++c)
            S += pm[(t * 25 + c) * 2 + 1] * expf(pm[(t * 25 + c) * 2] - M);
        MS[t * 2] = M;
        MS[t * 2 + 1] = 1.f / S;
    }
}

// ---------------- softmax normalize (in place on logits) ----------------
__global__ void k_norm(float* __restrict__ pi, const float* __restrict__ MS) {
    int p = blockIdx.x * blockDim.x + threadIdx.x;
    if (p < NB * NP) {
        int b = p / NP;
        pi[p] = expf(pi[p] - MS[b * 2]) * MS[b * 2 + 1];
    }
}

extern "C" void kernel_launch(void* const* d_in, const int* in_sizes, int n_in,
                              void* d_out, int out_size, void* d_ws, size_t ws_size,
                              hipStream_t stream) {
    const float* x        = (const float*)d_in[0];
    const int*   ei       = (const int*)d_in[1];
    // d_in[2] = batch_ids (unused: graphs are contiguous 225-node blocks)
    const float* g0_w1    = (const float*)d_in[3];
    const float* g0_b1    = (const float*)d_in[4];
    const float* g0_gamma = (const float*)d_in[5];
    const float* g0_beta  = (const float*)d_in[6];
    const float* g0_w2    = (const float*)d_in[7];
    const float* g0_b2    = (const float*)d_in[8];
    const float* g1_w1    = (const float*)d_in[9];
    const float* g1_b1    = (const float*)d_in[10];
    const float* g1_gamma = (const float*)d_in[11];
    const float* g1_beta  = (const float*)d_in[12];
    const float* g1_w2    = (const float*)d_in[13];
    const float* g1_b2    = (const float*)d_in[14];
    const float* a_w1     = (const float*)d_in[15];
    const float* a_b1     = (const float*)d_in[16];
    const float* a_w2     = (const float*)d_in[17];
    const float* a_b2     = (const float*)d_in[18];
    const float* c_w1     = (const float*)d_in[19];
    const float* c_b1     = (const float*)d_in[20];
    const float* c_w2     = (const float*)d_in[21];
    const float* c_b2     = (const float*)d_in[22];

    float* ws    = (float*)d_ws;
    float* agg0  = ws + WS_AGG0;
    float* agg1  = ws + WS_AGG1;
    float* sum0  = ws + WS_SUM0;
    float* sq0   = ws + WS_SQ0;
    float* sum1  = ws + WS_SUM1;
    float* sq1   = ws + WS_SQ1;
    float* pm    = ws + WS_PM;
    float* MS    = ws + WS_MS;
    float* tpre  = ws + WS_TPRE;
    float* h1    = ws + WS_H1;
    float* feats = ws + WS_FEATS;
    float* P1    = ws + WS_P1;
    float* P2    = ws + WS_P2;
    float* Ps    = ws + WS_PS;

    float* pi        = (float*)d_out;            // [8, 50625]
    float* value_out = (float*)d_out + NB * NP;  // [8]

    // zero the accumulator region (ws is poisoned to 0xAA before every call)
    hipMemsetAsync(d_ws, 0, WS_ZERO_FLOATS * sizeof(float), stream);

    k_scatter0<<<(NE * 2 + 255) / 256, 256, 0, stream>>>(x, ei, agg0);
    k_lin0<<<(NT + 15) / 16, 256, 0, stream>>>(x, agg0, g0_w1, g0_b1, tpre, sum0, sq0);
    k_bnlin0<<<NT / 4, 256, 0, stream>>>(tpre, sum0, sq0, g0_gamma, g0_beta, g0_w2, g0_b2, h1);
    k_scatter1<<<(NE * 16) / 256, 256, 0, stream>>>(h1, ei, agg1);
    k_lin1<<<(NT + 15) / 16, 256, 0, stream>>>(h1, agg1, g1_w1, g1_b1, tpre, sum1, sq1);
    k_bnlin1proj<<<NT / 4, 256, 0, stream>>>(tpre, sum1, sq1, g1_gamma, g1_beta, g1_w2, g1_b2,
                                             a_w1, feats, P1, P2);
    k_heads<<<1, 512, 0, stream>>>(feats, a_w1, a_b1, c_w1, c_b1, c_w2, c_b2, Ps, value_out);
    k_pairs<<<NB * 25, 256, 0, stream>>>(P1, P2, Ps, a_w2, a_b2, pi, pm);
    k_combine<<<1, 64, 0, stream>>>(pm, MS);
    k_norm<<<(NB * NP + 255) / 256, 256, 0, stream>>>(pi, MS);
}